// Round 10
// baseline (298.606 us; speedup 1.0000x reference)
//
#include <hip/hip_runtime.h>
#include <hip/hip_fp16.h>

// Wavelet lifting net, MI355X — 4 launches, packed-f16 math, 4x4 out/thread.
// 64x32 tiles, 128-thr blocks (grid 1536 = 6 blk/CU x 2 waves = 12 waves/CU).
// Input window loaded via VOLATILE LDS reads so the compiler cannot
// rematerialize it inside the channel loop (R8 showed VGPR=64 + LDS re-reads);
// __launch_bounds__(128,2) gives a 256-VGPR budget to hold it.
//  MODE0: in = YUV(x) even rows (on the fly, side-writes L); io = YUV odd;
//         dst = Hb' (ws).
//  MODE1: in = Hb' (halo); io = L; dst = L' (in-place in ws).
//  MODE2: in = even cols of L'/Hb'; io = odd cols; dst = d_out q1/q3. (T wts)
//  MODE3: in = d_out q1/q3; io = even cols; dst = d_out q0/q2.        (T wts)
// Hidden map is zero OUTSIDE the image (conv2 SAME pads hidden map):
// row-invalid folded into bias=-60000 (relu->0), col mask on edge blocks.
// conv2 accumulated f16 per 4-channel group, folded to fp32.

#define P1 (24*256*512)

__device__ __forceinline__ __half2 oddpair(__half2 a, __half2 b) {
  unsigned ua = __builtin_bit_cast(unsigned, a), ub = __builtin_bit_cast(unsigned, b);
  unsigned r = __builtin_amdgcn_alignbit(ub, ua, 16);
  return __builtin_bit_cast(__half2, r);
}

__device__ __forceinline__ __half2 relu2(__half2 s) {
  unsigned u = __builtin_bit_cast(unsigned, s), r;
  asm("v_pk_max_f16 %0, %1, 0" : "=v"(r) : "v"(u));
  return __builtin_bit_cast(__half2, r);
}

template<int MODE>
__global__ __launch_bounds__(128, 2) void k_subnet(
    const float* __restrict__ xp, float* __restrict__ ws, float* __restrict__ outp,
    const float* __restrict__ W1, const float* __restrict__ B1,
    const float* __restrict__ W2, const float* __restrict__ B2)
{
  constexpr int  IW    = (MODE <= 1) ? 512 : 256;
  constexpr int  HW    = 256 * IW;
  constexpr float sign = (MODE == 0 || MODE == 2) ? -1.f : 1.f;
  constexpr int  TRANS = (MODE >= 2) ? 1 : 0;

  __shared__ __align__(16) __half2 sW[16*20];   // per ch: w1[0..8], b1, w2[10..18], pad
  __shared__ __align__(16) __half  sIn[36*72];  // 64x32 tile + halo 2, stride 72

  const int z     = blockIdx.z;
  const int n     = (MODE >= 2) ? (z % 24) : z;
  const int which = (MODE >= 2) ? (z / 24) : 0;
  const int c_ = n >> 3, b_ = n & 7;
  const int x0 = blockIdx.x * 64, y0 = blockIdx.y * 32;
  const int tid = threadIdx.x;
  float* Lw = ws;
  float* Hw = ws + P1;

  // ---- weights -> LDS as broadcast half2 (transposed 3x3 if TRANS) ----
  for (int i = tid; i < 320; i += 128) {
    int cc = i / 20, j = i - cc*20;
    float v = 0.f;
    if (j < 9)       { int jt = TRANS ? ((j%3)*3 + j/3) : j; v = W1[cc*9 + jt]; }
    else if (j == 9) v = B1[cc];
    else if (j < 19) { int k = j - 10; int jt = TRANS ? ((k%3)*3 + k/3) : k; v = W2[cc*9 + jt]; }
    __half h = __float2half(v);
    sW[i] = __halves2half2(h, h);
  }

  // ---- input staging (36x68 halo-2 window, stride 72) ----
  float m0 = 0.f, m1 = 0.f, m2 = 0.f;
  if (MODE == 0) {
    m0 = (c_==0) ? 0.299f : ((c_==1) ? -0.147f :  0.615f);
    m1 = (c_==0) ? 0.587f : ((c_==1) ? -0.289f : -0.515f);
    m2 = (c_==0) ? 0.114f : ((c_==1) ?  0.436f : -0.100f);
  }
  for (int i = tid; i < 36*68; i += 128) {
    int ly = i / 68, lx = i - ly*68;
    int gy = y0 + ly - 2, gx = x0 + lx - 2;
    float v = 0.f;
    if ((unsigned)gy < 256u && (unsigned)gx < (unsigned)IW) {
      if (MODE == 0) {
        const float* xb = xp + ((long)b_*3*512 + 2*gy)*512 + gx;
        v = m0*xb[0] + m1*xb[262144] + m2*xb[524288];
        Lw[(long)n*HW + gy*IW + gx] = v;            // side-product L (f32)
      } else if (MODE == 1) {
        v = Hw[(long)n*HW + gy*IW + gx];
      } else if (MODE == 2) {
        const float* s = (which ? Hw : Lw) + (long)n*(256*512);
        v = s[gy*512 + 2*gx];                        // even cols
      } else {
        const float* s = outp + (long)(b_*12 + (which?9:3) + c_)*65536;
        v = s[gy*256 + gx];
      }
    }
    sIn[ly*72 + lx] = __float2half(v);
  }
  __syncthreads();

  const int tx = tid & 15, ty = tid >> 4;        // 16 x 8 threads
  const int oy = y0 + ty*4, ox = x0 + tx*4;      // 4x4 outputs per thread

  // ---- io prefetch (4 rows of float4) ----
  float4 iov[4];
  if (MODE == 0) {
#pragma unroll
    for (int r = 0; r < 4; ++r) {
      const float* xb = xp + ((long)b_*3*512 + (2*(oy+r)+1))*512 + ox;
      float4 rr = *(const float4*)&xb[0];
      float4 gg = *(const float4*)&xb[262144];
      float4 bb = *(const float4*)&xb[524288];
      iov[r] = make_float4(m0*rr.x + m1*gg.x + m2*bb.x,
                           m0*rr.y + m1*gg.y + m2*bb.y,
                           m0*rr.z + m1*gg.z + m2*bb.z,
                           m0*rr.w + m1*gg.w + m2*bb.w);
    }
  } else if (MODE == 1) {
    const float* s = Lw + (long)n*HW;
#pragma unroll
    for (int r = 0; r < 4; ++r) iov[r] = *(const float4*)&s[(oy+r)*IW + ox];
  } else {
    const float* s = (which ? Hw : Lw) + (long)n*(256*512);
#pragma unroll
    for (int r = 0; r < 4; ++r) {
      float4 a = *(const float4*)&s[(oy+r)*512 + 2*ox];
      float4 b = *(const float4*)&s[(oy+r)*512 + 2*ox + 4];
      iov[r] = (MODE == 2) ? make_float4(a.y, a.w, b.y, b.w)    // odd cols
                           : make_float4(a.x, a.z, b.x, b.z);   // even cols
    }
  }

  // ---- 8x8 input window: VOLATILE LDS loads (blocks remat), then odd pairs
  __half2 E[8][4], O[8][3];
#pragma unroll
  for (int r = 0; r < 8; ++r) {
    const volatile unsigned* row = (const volatile unsigned*)&sIn[(ty*4 + r)*72 + tx*4];
    unsigned u0 = row[0], u1 = row[1], u2 = row[2], u3 = row[3];
    E[r][0] = __builtin_bit_cast(__half2, u0);
    E[r][1] = __builtin_bit_cast(__half2, u1);
    E[r][2] = __builtin_bit_cast(__half2, u2);
    E[r][3] = __builtin_bit_cast(__half2, u3);
    O[r][0] = oddpair(E[r][0], E[r][1]);
    O[r][1] = oddpair(E[r][1], E[r][2]);
    O[r][2] = oddpair(E[r][2], E[r][3]);
  }

  // ---- hidden-map validity ----
  const bool edgex = (x0 == 0) || (x0 + 64 == IW);
  bool rowok[6];
#pragma unroll
  for (int k = 0; k < 6; ++k) rowok[k] = ((unsigned)(oy - 1 + k) < 256u);
  __half2 mE[3];
  if (edgex) {
#pragma unroll
    for (int p = 0; p < 3; ++p) {
      float a = ((unsigned)(ox - 1 + 2*p) < (unsigned)IW) ? 1.f : 0.f;
      float b = ((unsigned)(ox     + 2*p) < (unsigned)IW) ? 1.f : 0.f;
      mE[p] = __halves2half2(__float2half(a), __float2half(b));
    }
  }

  const __half2 zero2 = __builtin_bit_cast(__half2, 0u);
  const __half2 negb  = __halves2half2(__float2half(-60000.f), __float2half(-60000.f));

  float   ACCF[4][4] = {{0,0,0,0},{0,0,0,0},{0,0,0,0},{0,0,0,0}};
  __half2 ACC2[4][2] = {{zero2,zero2},{zero2,zero2},{zero2,zero2},{zero2,zero2}};

  auto loadW = [&](int cc, __half2* wv) {
    const float4* wq = (const float4*)&sW[cc*20];
#pragma unroll
    for (int q = 0; q < 5; ++q) {
      float4 f = wq[q];
      wv[4*q+0] = __builtin_bit_cast(__half2, f.x);
      wv[4*q+1] = __builtin_bit_cast(__half2, f.y);
      wv[4*q+2] = __builtin_bit_cast(__half2, f.z);
      wv[4*q+3] = __builtin_bit_cast(__half2, f.w);
    }
  };

  auto compute = [&](const __half2* wv, int c) {
    __half2 bias[6];
#pragma unroll
    for (int k = 0; k < 6; ++k) bias[k] = rowok[k] ? wv[9] : negb;
#pragma unroll
    for (int kk = 0; kk < 6; ++kk) {
      __half2 HE[3];
#pragma unroll
      for (int p = 0; p < 3; ++p) {
        __half2 hs = bias[kk];
#pragma unroll
        for (int dy = 0; dy < 3; ++dy) {
          hs = __hfma2(wv[dy*3+0], E[kk+dy][p],   hs);
          hs = __hfma2(wv[dy*3+1], O[kk+dy][p],   hs);
          hs = __hfma2(wv[dy*3+2], E[kk+dy][p+1], hs);
        }
        HE[p] = relu2(hs);
      }
      if (edgex) {
        HE[0] = __hmul2(HE[0], mE[0]);
        HE[1] = __hmul2(HE[1], mE[1]);
        HE[2] = __hmul2(HE[2], mE[2]);
      }
      __half2 HO0 = oddpair(HE[0], HE[1]);
      __half2 HO1 = oddpair(HE[1], HE[2]);
#pragma unroll
      for (int dy = 0; dy < 3; ++dy) {
        const int r = kk - dy;
        if (r >= 0 && r < 4) {
#pragma unroll
          for (int cp = 0; cp < 2; ++cp) {
            __half2 a = ACC2[r][cp];
            a = __hfma2(wv[10+dy*3+0], HE[cp],           a);
            a = __hfma2(wv[10+dy*3+1], (cp ? HO1 : HO0), a);
            a = __hfma2(wv[10+dy*3+2], HE[cp+1],         a);
            ACC2[r][cp] = a;
          }
        }
      }
    }
    if ((c & 3) == 3) {      // fold f16 group accumulator into fp32
#pragma unroll
      for (int r = 0; r < 4; ++r)
#pragma unroll
        for (int cp = 0; cp < 2; ++cp) {
          ACCF[r][2*cp]   += __low2float(ACC2[r][cp]);
          ACCF[r][2*cp+1] += __high2float(ACC2[r][cp]);
          ACC2[r][cp] = zero2;
        }
    }
  };

  __half2 wA[20], wB[20];
  loadW(0, wA);
#pragma unroll 1
  for (int c = 0; c < 16; c += 2) {
    loadW(c + 1, wB);
    compute(wA, c);
    if (c + 2 < 16) loadW(c + 2, wA);
    compute(wB, c + 1);
  }

  // ---- epilogue: out = io + sign*(acc + b2) ----
  const float b2 = B2[0];
  float* dst;
  if      (MODE == 0) dst = Hw + (long)n*HW;
  else if (MODE == 1) dst = Lw + (long)n*HW;
  else if (MODE == 2) dst = outp + (long)(b_*12 + (which?9:3) + c_)*65536;
  else                dst = outp + (long)(b_*12 + (which?6:0) + c_)*65536;

#pragma unroll
  for (int r = 0; r < 4; ++r) {
    float4 v;
    v.x = iov[r].x + sign * (ACCF[r][0] + b2);
    v.y = iov[r].y + sign * (ACCF[r][1] + b2);
    v.z = iov[r].z + sign * (ACCF[r][2] + b2);
    v.w = iov[r].w + sign * (ACCF[r][3] + b2);
    *(float4*)&dst[(oy + r)*IW + ox] = v;
  }
}

extern "C" void kernel_launch(void* const* d_in, const int* in_sizes, int n_in,
                              void* d_out, int out_size, void* d_ws, size_t ws_size,
                              hipStream_t stream) {
  const float* x   = (const float*)d_in[0];
  const float* Wp1 = (const float*)d_in[1];
  const float* bp1 = (const float*)d_in[2];
  const float* Wp2 = (const float*)d_in[3];
  const float* bp2 = (const float*)d_in[4];
  const float* Wu1 = (const float*)d_in[5];
  const float* bu1 = (const float*)d_in[6];
  const float* Wu2 = (const float*)d_in[7];
  const float* bu2 = (const float*)d_in[8];
  float* out = (float*)d_out;
  float* ws  = (float*)d_ws;

  // S1P: Hb' = Hb - p(L); materializes L
  k_subnet<0><<<dim3(8,8,24), 128, 0, stream>>>(x, ws, out, Wp1, bp1, Wp2, bp2);
  // S1U: L' = L + u(Hb')
  k_subnet<1><<<dim3(8,8,24), 128, 0, stream>>>(x, ws, out, Wu1, bu1, Wu2, bu2);
  // S2P: HL' = HL - pT(LL) -> q1 ; HH' = HH - pT(LH) -> q3
  k_subnet<2><<<dim3(4,8,48), 128, 0, stream>>>(x, ws, out, Wp1, bp1, Wp2, bp2);
  // S2U: LL' = LL + uT(HL') -> q0 ; LH' = LH + uT(HH') -> q2
  k_subnet<3><<<dim3(4,8,48), 128, 0, stream>>>(x, ws, out, Wu1, bu1, Wu2, bu2);
}

// Round 11
// 278.142 us; speedup vs baseline: 1.0736x; 1.0736x over previous
//
#include <hip/hip_runtime.h>
#include <hip/hip_fp16.h>

// Wavelet lifting net, MI355X — 4 launches, packed-f16 math, 4x4 out/thread.
// R8 geometry (64x64 tile, 256-thread blocks, grid 768 = 3 blk/CU) +
// latency fixes: volatile E-window loads (pin in VGPRs), weight ping-pong
// (ds_reads one channel ahead), io prefetch before the channel loop.
//  MODE0: in = YUV(x) even rows (on the fly, side-writes L); io = YUV odd;
//         dst = Hb' (ws).
//  MODE1: in = Hb' (halo); io = L; dst = L' (in-place in ws).
//  MODE2: in = even cols of L'/Hb'; io = odd cols; dst = d_out q1/q3. (T wts)
//  MODE3: in = d_out q1/q3; io = even cols; dst = d_out q0/q2.        (T wts)
// Hidden map is zero OUTSIDE the image (conv2 SAME pads hidden map):
// row-invalid folded into bias=-60000 (relu->0), col mask on edge blocks.
// conv2 accumulated f16 per 4-channel group, folded to fp32.

#define P1 (24*256*512)

__device__ __forceinline__ __half2 oddpair(__half2 a, __half2 b) {
  unsigned ua = __builtin_bit_cast(unsigned, a), ub = __builtin_bit_cast(unsigned, b);
  unsigned r = __builtin_amdgcn_alignbit(ub, ua, 16);
  return __builtin_bit_cast(__half2, r);
}

__device__ __forceinline__ __half2 relu2(__half2 s) {
  unsigned u = __builtin_bit_cast(unsigned, s), r;
  asm("v_pk_max_f16 %0, %1, 0" : "=v"(r) : "v"(u));
  return __builtin_bit_cast(__half2, r);
}

template<int MODE>
__global__ __launch_bounds__(256, 3) void k_subnet(
    const float* __restrict__ xp, float* __restrict__ ws, float* __restrict__ outp,
    const float* __restrict__ W1, const float* __restrict__ B1,
    const float* __restrict__ W2, const float* __restrict__ B2)
{
  constexpr int  IW    = (MODE <= 1) ? 512 : 256;
  constexpr int  HW    = 256 * IW;
  constexpr float sign = (MODE == 0 || MODE == 2) ? -1.f : 1.f;
  constexpr int  TRANS = (MODE >= 2) ? 1 : 0;

  __shared__ __align__(16) __half2 sW[16*20];   // per ch: w1[0..8], b1, w2[10..18], pad
  __shared__ __align__(16) __half  sIn[68*72];  // 64x64 tile + halo 2, stride 72

  const int z     = blockIdx.z;
  const int n     = (MODE >= 2) ? (z % 24) : z;
  const int which = (MODE >= 2) ? (z / 24) : 0;
  const int c_ = n >> 3, b_ = n & 7;
  const int x0 = blockIdx.x * 64, y0 = blockIdx.y * 64;
  const int tid = threadIdx.x;
  float* Lw = ws;
  float* Hw = ws + P1;

  // ---- weights -> LDS as broadcast half2 (transposed 3x3 if TRANS) ----
  for (int i = tid; i < 320; i += 256) {
    int cc = i / 20, j = i - cc*20;
    float v = 0.f;
    if (j < 9)       { int jt = TRANS ? ((j%3)*3 + j/3) : j; v = W1[cc*9 + jt]; }
    else if (j == 9) v = B1[cc];
    else if (j < 19) { int k = j - 10; int jt = TRANS ? ((k%3)*3 + k/3) : k; v = W2[cc*9 + jt]; }
    __half h = __float2half(v);
    sW[i] = __halves2half2(h, h);
  }

  // ---- input staging (68x68 halo-2 window, stride 72) ----
  float m0 = 0.f, m1 = 0.f, m2 = 0.f;
  if (MODE == 0) {
    m0 = (c_==0) ? 0.299f : ((c_==1) ? -0.147f :  0.615f);
    m1 = (c_==0) ? 0.587f : ((c_==1) ? -0.289f : -0.515f);
    m2 = (c_==0) ? 0.114f : ((c_==1) ?  0.436f : -0.100f);
  }
  for (int i = tid; i < 68*68; i += 256) {
    int ly = i / 68, lx = i - ly*68;
    int gy = y0 + ly - 2, gx = x0 + lx - 2;
    float v = 0.f;
    if ((unsigned)gy < 256u && (unsigned)gx < (unsigned)IW) {
      if (MODE == 0) {
        const float* xb = xp + ((long)b_*3*512 + 2*gy)*512 + gx;
        v = m0*xb[0] + m1*xb[262144] + m2*xb[524288];
        Lw[(long)n*HW + gy*IW + gx] = v;            // side-product L (f32)
      } else if (MODE == 1) {
        v = Hw[(long)n*HW + gy*IW + gx];
      } else if (MODE == 2) {
        const float* s = (which ? Hw : Lw) + (long)n*(256*512);
        v = s[gy*512 + 2*gx];                        // even cols
      } else {
        const float* s = outp + (long)(b_*12 + (which?9:3) + c_)*65536;
        v = s[gy*256 + gx];
      }
    }
    sIn[ly*72 + lx] = __float2half(v);
  }
  __syncthreads();

  const int tx = tid & 15, ty = tid >> 4;        // 16 x 16 threads
  const int oy = y0 + ty*4, ox = x0 + tx*4;      // 4x4 outputs per thread

  // ---- io prefetch (4 rows of float4) ----
  float4 iov[4];
  if (MODE == 0) {
#pragma unroll
    for (int r = 0; r < 4; ++r) {
      const float* xb = xp + ((long)b_*3*512 + (2*(oy+r)+1))*512 + ox;
      float4 rr = *(const float4*)&xb[0];
      float4 gg = *(const float4*)&xb[262144];
      float4 bb = *(const float4*)&xb[524288];
      iov[r] = make_float4(m0*rr.x + m1*gg.x + m2*bb.x,
                           m0*rr.y + m1*gg.y + m2*bb.y,
                           m0*rr.z + m1*gg.z + m2*bb.z,
                           m0*rr.w + m1*gg.w + m2*bb.w);
    }
  } else if (MODE == 1) {
    const float* s = Lw + (long)n*HW;
#pragma unroll
    for (int r = 0; r < 4; ++r) iov[r] = *(const float4*)&s[(oy+r)*IW + ox];
  } else {
    const float* s = (which ? Hw : Lw) + (long)n*(256*512);
#pragma unroll
    for (int r = 0; r < 4; ++r) {
      float4 a = *(const float4*)&s[(oy+r)*512 + 2*ox];
      float4 b = *(const float4*)&s[(oy+r)*512 + 2*ox + 4];
      iov[r] = (MODE == 2) ? make_float4(a.y, a.w, b.y, b.w)    // odd cols
                           : make_float4(a.x, a.z, b.x, b.z);   // even cols
    }
  }

  // ---- 8x8 input window: VOLATILE LDS loads (blocks remat), then odd pairs
  __half2 E[8][4], O[8][3];
#pragma unroll
  for (int r = 0; r < 8; ++r) {
    const volatile unsigned* row = (const volatile unsigned*)&sIn[(ty*4 + r)*72 + tx*4];
    unsigned u0 = row[0], u1 = row[1], u2 = row[2], u3 = row[3];
    E[r][0] = __builtin_bit_cast(__half2, u0);
    E[r][1] = __builtin_bit_cast(__half2, u1);
    E[r][2] = __builtin_bit_cast(__half2, u2);
    E[r][3] = __builtin_bit_cast(__half2, u3);
    O[r][0] = oddpair(E[r][0], E[r][1]);
    O[r][1] = oddpair(E[r][1], E[r][2]);
    O[r][2] = oddpair(E[r][2], E[r][3]);
  }

  // ---- hidden-map validity ----
  const bool edgex = (x0 == 0) || (x0 + 64 == IW);
  bool rowok[6];
#pragma unroll
  for (int k = 0; k < 6; ++k) rowok[k] = ((unsigned)(oy - 1 + k) < 256u);
  __half2 mE[3];
  if (edgex) {
#pragma unroll
    for (int p = 0; p < 3; ++p) {
      float a = ((unsigned)(ox - 1 + 2*p) < (unsigned)IW) ? 1.f : 0.f;
      float b = ((unsigned)(ox     + 2*p) < (unsigned)IW) ? 1.f : 0.f;
      mE[p] = __halves2half2(__float2half(a), __float2half(b));
    }
  }

  const __half2 zero2 = __builtin_bit_cast(__half2, 0u);
  const __half2 negb  = __halves2half2(__float2half(-60000.f), __float2half(-60000.f));

  float   ACCF[4][4] = {{0,0,0,0},{0,0,0,0},{0,0,0,0},{0,0,0,0}};
  __half2 ACC2[4][2] = {{zero2,zero2},{zero2,zero2},{zero2,zero2},{zero2,zero2}};

  auto loadW = [&](int cc, __half2* wv) {
    const float4* wq = (const float4*)&sW[cc*20];
#pragma unroll
    for (int q = 0; q < 5; ++q) {
      float4 f = wq[q];
      wv[4*q+0] = __builtin_bit_cast(__half2, f.x);
      wv[4*q+1] = __builtin_bit_cast(__half2, f.y);
      wv[4*q+2] = __builtin_bit_cast(__half2, f.z);
      wv[4*q+3] = __builtin_bit_cast(__half2, f.w);
    }
  };

  auto compute = [&](const __half2* wv, int c) {
    __half2 bias[6];
#pragma unroll
    for (int k = 0; k < 6; ++k) bias[k] = rowok[k] ? wv[9] : negb;
#pragma unroll
    for (int kk = 0; kk < 6; ++kk) {
      __half2 HE[3];
#pragma unroll
      for (int p = 0; p < 3; ++p) {
        __half2 hs = bias[kk];
#pragma unroll
        for (int dy = 0; dy < 3; ++dy) {
          hs = __hfma2(wv[dy*3+0], E[kk+dy][p],   hs);
          hs = __hfma2(wv[dy*3+1], O[kk+dy][p],   hs);
          hs = __hfma2(wv[dy*3+2], E[kk+dy][p+1], hs);
        }
        HE[p] = relu2(hs);
      }
      if (edgex) {
        HE[0] = __hmul2(HE[0], mE[0]);
        HE[1] = __hmul2(HE[1], mE[1]);
        HE[2] = __hmul2(HE[2], mE[2]);
      }
      __half2 HO0 = oddpair(HE[0], HE[1]);
      __half2 HO1 = oddpair(HE[1], HE[2]);
#pragma unroll
      for (int dy = 0; dy < 3; ++dy) {
        const int r = kk - dy;
        if (r >= 0 && r < 4) {
#pragma unroll
          for (int cp = 0; cp < 2; ++cp) {
            __half2 a = ACC2[r][cp];
            a = __hfma2(wv[10+dy*3+0], HE[cp],           a);
            a = __hfma2(wv[10+dy*3+1], (cp ? HO1 : HO0), a);
            a = __hfma2(wv[10+dy*3+2], HE[cp+1],         a);
            ACC2[r][cp] = a;
          }
        }
      }
    }
    if ((c & 3) == 3) {      // fold f16 group accumulator into fp32
#pragma unroll
      for (int r = 0; r < 4; ++r)
#pragma unroll
        for (int cp = 0; cp < 2; ++cp) {
          ACCF[r][2*cp]   += __low2float(ACC2[r][cp]);
          ACCF[r][2*cp+1] += __high2float(ACC2[r][cp]);
          ACC2[r][cp] = zero2;
        }
    }
  };

  __half2 wA[20], wB[20];
  loadW(0, wA);
#pragma unroll 1
  for (int c = 0; c < 16; c += 2) {
    loadW(c + 1, wB);
    compute(wA, c);
    if (c + 2 < 16) loadW(c + 2, wA);
    compute(wB, c + 1);
  }

  // ---- epilogue: out = io + sign*(acc + b2) ----
  const float b2 = B2[0];
  float* dst;
  if      (MODE == 0) dst = Hw + (long)n*HW;
  else if (MODE == 1) dst = Lw + (long)n*HW;
  else if (MODE == 2) dst = outp + (long)(b_*12 + (which?9:3) + c_)*65536;
  else                dst = outp + (long)(b_*12 + (which?6:0) + c_)*65536;

#pragma unroll
  for (int r = 0; r < 4; ++r) {
    float4 v;
    v.x = iov[r].x + sign * (ACCF[r][0] + b2);
    v.y = iov[r].y + sign * (ACCF[r][1] + b2);
    v.z = iov[r].z + sign * (ACCF[r][2] + b2);
    v.w = iov[r].w + sign * (ACCF[r][3] + b2);
    *(float4*)&dst[(oy + r)*IW + ox] = v;
  }
}

extern "C" void kernel_launch(void* const* d_in, const int* in_sizes, int n_in,
                              void* d_out, int out_size, void* d_ws, size_t ws_size,
                              hipStream_t stream) {
  const float* x   = (const float*)d_in[0];
  const float* Wp1 = (const float*)d_in[1];
  const float* bp1 = (const float*)d_in[2];
  const float* Wp2 = (const float*)d_in[3];
  const float* bp2 = (const float*)d_in[4];
  const float* Wu1 = (const float*)d_in[5];
  const float* bu1 = (const float*)d_in[6];
  const float* Wu2 = (const float*)d_in[7];
  const float* bu2 = (const float*)d_in[8];
  float* out = (float*)d_out;
  float* ws  = (float*)d_ws;

  // S1P: Hb' = Hb - p(L); materializes L
  k_subnet<0><<<dim3(8,4,24), 256, 0, stream>>>(x, ws, out, Wp1, bp1, Wp2, bp2);
  // S1U: L' = L + u(Hb')
  k_subnet<1><<<dim3(8,4,24), 256, 0, stream>>>(x, ws, out, Wu1, bu1, Wu2, bu2);
  // S2P: HL' = HL - pT(LL) -> q1 ; HH' = HH - pT(LH) -> q3
  k_subnet<2><<<dim3(4,4,48), 256, 0, stream>>>(x, ws, out, Wp1, bp1, Wp2, bp2);
  // S2U: LL' = LL + uT(HL') -> q0 ; LH' = LH + uT(HH') -> q2
  k_subnet<3><<<dim3(4,4,48), 256, 0, stream>>>(x, ws, out, Wu1, bu1, Wu2, bu2);
}

// Round 12
// 256.598 us; speedup vs baseline: 1.1637x; 1.0840x over previous
//
#include <hip/hip_runtime.h>
#include <hip/hip_fp16.h>

// Wavelet lifting net, MI355X — 4 launches, packed-f16 math, 4x4 out/thread.
// R8 geometry (64x64 tile, 256-thr blocks, grid 768) with a ROLLING 3-row
// input window (re-read from LDS per channel) so the live register set fits
// the allocator's budget by construction. No lambdas (R9-R11 regression:
// lambda-pointer arrays fell to scratch => 40MB spill traffic), no volatile.
//  MODE0: in = YUV(x) even rows (on the fly, side-writes L); io = YUV odd;
//         dst = Hb' (ws).
//  MODE1: in = Hb' (halo); io = L; dst = L' (in-place in ws).
//  MODE2: in = even cols of L'/Hb'; io = odd cols; dst = d_out q1/q3. (T wts)
//  MODE3: in = d_out q1/q3; io = even cols; dst = d_out q0/q2.        (T wts)
// Hidden map is zero OUTSIDE the image (conv2 SAME pads hidden map):
// row-invalid folded into bias=-60000 (relu->0), col mask on edge blocks.
// conv2 accumulated f16 per 4-channel group, folded to fp32.

#define P1 (24*256*512)

__device__ __forceinline__ __half2 oddpair(__half2 a, __half2 b) {
  unsigned ua = __builtin_bit_cast(unsigned, a), ub = __builtin_bit_cast(unsigned, b);
  unsigned r = __builtin_amdgcn_alignbit(ub, ua, 16);
  return __builtin_bit_cast(__half2, r);
}

__device__ __forceinline__ __half2 relu2(__half2 s) {
  unsigned u = __builtin_bit_cast(unsigned, s), r;
  asm("v_pk_max_f16 %0, %1, 0" : "=v"(r) : "v"(u));
  return __builtin_bit_cast(__half2, r);
}

template<int MODE>
__global__ __launch_bounds__(256, 3) void k_subnet(
    const float* __restrict__ xp, float* __restrict__ ws, float* __restrict__ outp,
    const float* __restrict__ W1, const float* __restrict__ B1,
    const float* __restrict__ W2, const float* __restrict__ B2)
{
  constexpr int  IW    = (MODE <= 1) ? 512 : 256;
  constexpr int  HW    = 256 * IW;
  constexpr float sign = (MODE == 0 || MODE == 2) ? -1.f : 1.f;
  constexpr int  TRANS = (MODE >= 2) ? 1 : 0;

  __shared__ __align__(16) __half2 sW[16*20];   // per ch: w1[0..8], b1, w2[10..18], pad
  __shared__ __align__(16) __half  sIn[68*72];  // 64x64 tile + halo 2, stride 72

  const int z     = blockIdx.z;
  const int n     = (MODE >= 2) ? (z % 24) : z;
  const int which = (MODE >= 2) ? (z / 24) : 0;
  const int c_ = n >> 3, b_ = n & 7;
  const int x0 = blockIdx.x * 64, y0 = blockIdx.y * 64;
  const int tid = threadIdx.x;
  float* Lw = ws;
  float* Hw = ws + P1;

  // ---- weights -> LDS as broadcast half2 (transposed 3x3 if TRANS) ----
  for (int i = tid; i < 320; i += 256) {
    int cc = i / 20, j = i - cc*20;
    float v = 0.f;
    if (j < 9)       { int jt = TRANS ? ((j%3)*3 + j/3) : j; v = W1[cc*9 + jt]; }
    else if (j == 9) v = B1[cc];
    else if (j < 19) { int k = j - 10; int jt = TRANS ? ((k%3)*3 + k/3) : k; v = W2[cc*9 + jt]; }
    __half h = __float2half(v);
    sW[i] = __halves2half2(h, h);
  }

  // ---- input staging (68x68 halo-2 window, stride 72) ----
  float m0 = 0.f, m1 = 0.f, m2 = 0.f;
  if (MODE == 0) {
    m0 = (c_==0) ? 0.299f : ((c_==1) ? -0.147f :  0.615f);
    m1 = (c_==0) ? 0.587f : ((c_==1) ? -0.289f : -0.515f);
    m2 = (c_==0) ? 0.114f : ((c_==1) ?  0.436f : -0.100f);
  }
  for (int i = tid; i < 68*68; i += 256) {
    int ly = i / 68, lx = i - ly*68;
    int gy = y0 + ly - 2, gx = x0 + lx - 2;
    float v = 0.f;
    if ((unsigned)gy < 256u && (unsigned)gx < (unsigned)IW) {
      if (MODE == 0) {
        const float* xb = xp + ((long)b_*3*512 + 2*gy)*512 + gx;
        v = m0*xb[0] + m1*xb[262144] + m2*xb[524288];
        Lw[(long)n*HW + gy*IW + gx] = v;            // side-product L (f32)
      } else if (MODE == 1) {
        v = Hw[(long)n*HW + gy*IW + gx];
      } else if (MODE == 2) {
        const float* s = (which ? Hw : Lw) + (long)n*(256*512);
        v = s[gy*512 + 2*gx];                        // even cols
      } else {
        const float* s = outp + (long)(b_*12 + (which?9:3) + c_)*65536;
        v = s[gy*256 + gx];
      }
    }
    sIn[ly*72 + lx] = __float2half(v);
  }
  __syncthreads();

  const int tx = tid & 15, ty = tid >> 4;        // 16 x 16 threads
  const int oy = y0 + ty*4, ox = x0 + tx*4;      // 4x4 outputs per thread
  const int rb = ty*4;                           // window base row in sIn

  // ---- hidden-map validity ----
  const bool edgex = (x0 == 0) || (x0 + 64 == IW);
  bool rowok[6];
#pragma unroll
  for (int k = 0; k < 6; ++k) rowok[k] = ((unsigned)(oy - 1 + k) < 256u);
  __half2 mE[3];
  if (edgex) {
#pragma unroll
    for (int p = 0; p < 3; ++p) {
      float a = ((unsigned)(ox - 1 + 2*p) < (unsigned)IW) ? 1.f : 0.f;
      float b = ((unsigned)(ox     + 2*p) < (unsigned)IW) ? 1.f : 0.f;
      mE[p] = __halves2half2(__float2half(a), __float2half(b));
    }
  }

  const __half2 zero2 = __builtin_bit_cast(__half2, 0u);
  const __half2 negb  = __halves2half2(__float2half(-60000.f), __float2half(-60000.f));

  float   ACCF[4][4] = {{0,0,0,0},{0,0,0,0},{0,0,0,0},{0,0,0,0}};
  __half2 ACC2[4][2] = {{zero2,zero2},{zero2,zero2},{zero2,zero2},{zero2,zero2}};

#pragma unroll 1
  for (int c = 0; c < 16; ++c) {
    // ---- weights for this channel (5 x 16B LDS reads, broadcast) ----
    __half2 wv[20];
    {
      const float4* wq = (const float4*)&sW[c*20];
#pragma unroll
      for (int q = 0; q < 5; ++q) {
        float4 f = wq[q];
        wv[4*q+0] = __builtin_bit_cast(__half2, f.x);
        wv[4*q+1] = __builtin_bit_cast(__half2, f.y);
        wv[4*q+2] = __builtin_bit_cast(__half2, f.z);
        wv[4*q+3] = __builtin_bit_cast(__half2, f.w);
      }
    }
    __half2 bias[6];
#pragma unroll
    for (int k = 0; k < 6; ++k) bias[k] = rowok[k] ? wv[9] : negb;

    // ---- rolling 3-row input window (re-read from LDS each channel) ----
    __half2 E[3][4], O[3][3];
#pragma unroll
    for (int r = 0; r < 2; ++r) {
      const __half2* row = (const __half2*)&sIn[(rb + r)*72 + tx*4];
      E[r][0] = row[0]; E[r][1] = row[1]; E[r][2] = row[2]; E[r][3] = row[3];
      O[r][0] = oddpair(E[r][0], E[r][1]);
      O[r][1] = oddpair(E[r][1], E[r][2]);
      O[r][2] = oddpair(E[r][2], E[r][3]);
    }

#pragma unroll
    for (int kk = 0; kk < 6; ++kk) {
      const int s0 = kk % 3, s1 = (kk+1) % 3, s2 = (kk+2) % 3;
      {
        const __half2* row = (const __half2*)&sIn[(rb + kk + 2)*72 + tx*4];
        E[s2][0] = row[0]; E[s2][1] = row[1]; E[s2][2] = row[2]; E[s2][3] = row[3];
        O[s2][0] = oddpair(E[s2][0], E[s2][1]);
        O[s2][1] = oddpair(E[s2][1], E[s2][2]);
        O[s2][2] = oddpair(E[s2][2], E[s2][3]);
      }
      __half2 HE[3];
#pragma unroll
      for (int p = 0; p < 3; ++p) {
        __half2 hs = bias[kk];
        hs = __hfma2(wv[0], E[s0][p],   hs);
        hs = __hfma2(wv[1], O[s0][p],   hs);
        hs = __hfma2(wv[2], E[s0][p+1], hs);
        hs = __hfma2(wv[3], E[s1][p],   hs);
        hs = __hfma2(wv[4], O[s1][p],   hs);
        hs = __hfma2(wv[5], E[s1][p+1], hs);
        hs = __hfma2(wv[6], E[s2][p],   hs);
        hs = __hfma2(wv[7], O[s2][p],   hs);
        hs = __hfma2(wv[8], E[s2][p+1], hs);
        HE[p] = relu2(hs);
      }
      if (edgex) {
        HE[0] = __hmul2(HE[0], mE[0]);
        HE[1] = __hmul2(HE[1], mE[1]);
        HE[2] = __hmul2(HE[2], mE[2]);
      }
      __half2 HO0 = oddpair(HE[0], HE[1]);
      __half2 HO1 = oddpair(HE[1], HE[2]);
#pragma unroll
      for (int dy = 0; dy < 3; ++dy) {
        const int r = kk - dy;
        if (r >= 0 && r < 4) {
#pragma unroll
          for (int cp = 0; cp < 2; ++cp) {
            __half2 a = ACC2[r][cp];
            a = __hfma2(wv[10+dy*3+0], HE[cp],           a);
            a = __hfma2(wv[10+dy*3+1], (cp ? HO1 : HO0), a);
            a = __hfma2(wv[10+dy*3+2], HE[cp+1],         a);
            ACC2[r][cp] = a;
          }
        }
      }
    }
    if ((c & 3) == 3) {      // fold f16 group accumulator into fp32
#pragma unroll
      for (int r = 0; r < 4; ++r)
#pragma unroll
        for (int cp = 0; cp < 2; ++cp) {
          ACCF[r][2*cp]   += __low2float(ACC2[r][cp]);
          ACCF[r][2*cp+1] += __high2float(ACC2[r][cp]);
          ACC2[r][cp] = zero2;
        }
    }
  }

  // ---- epilogue: out = io + sign*(acc + b2) ----
  const float b2 = B2[0];
  float4 iov[4];
  if (MODE == 0) {
#pragma unroll
    for (int r = 0; r < 4; ++r) {
      const float* xb = xp + ((long)b_*3*512 + (2*(oy+r)+1))*512 + ox;
      float4 rr = *(const float4*)&xb[0];
      float4 gg = *(const float4*)&xb[262144];
      float4 bb = *(const float4*)&xb[524288];
      iov[r] = make_float4(m0*rr.x + m1*gg.x + m2*bb.x,
                           m0*rr.y + m1*gg.y + m2*bb.y,
                           m0*rr.z + m1*gg.z + m2*bb.z,
                           m0*rr.w + m1*gg.w + m2*bb.w);
    }
  } else if (MODE == 1) {
    const float* s = Lw + (long)n*HW;
#pragma unroll
    for (int r = 0; r < 4; ++r) iov[r] = *(const float4*)&s[(oy+r)*IW + ox];
  } else {
    const float* s = (which ? Hw : Lw) + (long)n*(256*512);
#pragma unroll
    for (int r = 0; r < 4; ++r) {
      float4 a = *(const float4*)&s[(oy+r)*512 + 2*ox];
      float4 b = *(const float4*)&s[(oy+r)*512 + 2*ox + 4];
      iov[r] = (MODE == 2) ? make_float4(a.y, a.w, b.y, b.w)    // odd cols
                           : make_float4(a.x, a.z, b.x, b.z);   // even cols
    }
  }

  float* dst;
  if      (MODE == 0) dst = Hw + (long)n*HW;
  else if (MODE == 1) dst = Lw + (long)n*HW;
  else if (MODE == 2) dst = outp + (long)(b_*12 + (which?9:3) + c_)*65536;
  else                dst = outp + (long)(b_*12 + (which?6:0) + c_)*65536;

#pragma unroll
  for (int r = 0; r < 4; ++r) {
    float4 v;
    v.x = iov[r].x + sign * (ACCF[r][0] + b2);
    v.y = iov[r].y + sign * (ACCF[r][1] + b2);
    v.z = iov[r].z + sign * (ACCF[r][2] + b2);
    v.w = iov[r].w + sign * (ACCF[r][3] + b2);
    *(float4*)&dst[(oy + r)*IW + ox] = v;
  }
}

extern "C" void kernel_launch(void* const* d_in, const int* in_sizes, int n_in,
                              void* d_out, int out_size, void* d_ws, size_t ws_size,
                              hipStream_t stream) {
  const float* x   = (const float*)d_in[0];
  const float* Wp1 = (const float*)d_in[1];
  const float* bp1 = (const float*)d_in[2];
  const float* Wp2 = (const float*)d_in[3];
  const float* bp2 = (const float*)d_in[4];
  const float* Wu1 = (const float*)d_in[5];
  const float* bu1 = (const float*)d_in[6];
  const float* Wu2 = (const float*)d_in[7];
  const float* bu2 = (const float*)d_in[8];
  float* out = (float*)d_out;
  float* ws  = (float*)d_ws;

  // S1P: Hb' = Hb - p(L); materializes L
  k_subnet<0><<<dim3(8,4,24), 256, 0, stream>>>(x, ws, out, Wp1, bp1, Wp2, bp2);
  // S1U: L' = L + u(Hb')
  k_subnet<1><<<dim3(8,4,24), 256, 0, stream>>>(x, ws, out, Wu1, bu1, Wu2, bu2);
  // S2P: HL' = HL - pT(LL) -> q1 ; HH' = HH - pT(LH) -> q3
  k_subnet<2><<<dim3(4,4,48), 256, 0, stream>>>(x, ws, out, Wp1, bp1, Wp2, bp2);
  // S2U: LL' = LL + uT(HL') -> q0 ; LH' = LH + uT(HH') -> q2
  k_subnet<3><<<dim3(4,4,48), 256, 0, stream>>>(x, ws, out, Wu1, bu1, Wu2, bu2);
}

// Round 13
// 254.185 us; speedup vs baseline: 1.1748x; 1.0095x over previous
//
#include <hip/hip_runtime.h>
#include <hip/hip_fp16.h>

// Wavelet lifting net, MI355X — 4 launches, packed-f16 math, 4x4 out/thread.
// R12 base (64x64 tile, 256-thr blocks, rolling 3-row LDS window, no lambdas)
// + TWO channels per window pass (window reads/alignbits amortized 2x; both
// channels accumulate into the shared conv2 accumulator) + io prefetch
// hoisted before the channel loop.
//  MODE0: in = YUV(x) even rows (on the fly, side-writes L); io = YUV odd;
//         dst = Hb' (ws).
//  MODE1: in = Hb' (halo); io = L; dst = L' (in-place in ws).
//  MODE2: in = even cols of L'/Hb'; io = odd cols; dst = d_out q1/q3. (T wts)
//  MODE3: in = d_out q1/q3; io = even cols; dst = d_out q0/q2.        (T wts)
// Hidden map is zero OUTSIDE the image (conv2 SAME pads hidden map):
// row-invalid folded into bias=-60000 (relu->0), col mask on edge blocks.
// conv2 accumulated f16 per 4-channel group, folded to fp32.

#define P1 (24*256*512)

__device__ __forceinline__ __half2 oddpair(__half2 a, __half2 b) {
  unsigned ua = __builtin_bit_cast(unsigned, a), ub = __builtin_bit_cast(unsigned, b);
  unsigned r = __builtin_amdgcn_alignbit(ub, ua, 16);
  return __builtin_bit_cast(__half2, r);
}

__device__ __forceinline__ __half2 relu2(__half2 s) {
  unsigned u = __builtin_bit_cast(unsigned, s), r;
  asm("v_pk_max_f16 %0, %1, 0" : "=v"(r) : "v"(u));
  return __builtin_bit_cast(__half2, r);
}

template<int MODE>
__global__ __launch_bounds__(256, 3) void k_subnet(
    const float* __restrict__ xp, float* __restrict__ ws, float* __restrict__ outp,
    const float* __restrict__ W1, const float* __restrict__ B1,
    const float* __restrict__ W2, const float* __restrict__ B2)
{
  constexpr int  IW    = (MODE <= 1) ? 512 : 256;
  constexpr int  HW    = 256 * IW;
  constexpr float sign = (MODE == 0 || MODE == 2) ? -1.f : 1.f;
  constexpr int  TRANS = (MODE >= 2) ? 1 : 0;

  __shared__ __align__(16) __half2 sW[16*20];   // per ch: w1[0..8], b1, w2[10..18], pad
  __shared__ __align__(16) __half  sIn[68*72];  // 64x64 tile + halo 2, stride 72

  const int z     = blockIdx.z;
  const int n     = (MODE >= 2) ? (z % 24) : z;
  const int which = (MODE >= 2) ? (z / 24) : 0;
  const int c_ = n >> 3, b_ = n & 7;
  const int x0 = blockIdx.x * 64, y0 = blockIdx.y * 64;
  const int tid = threadIdx.x;
  float* Lw = ws;
  float* Hw = ws + P1;

  // ---- weights -> LDS as broadcast half2 (transposed 3x3 if TRANS) ----
  for (int i = tid; i < 320; i += 256) {
    int cc = i / 20, j = i - cc*20;
    float v = 0.f;
    if (j < 9)       { int jt = TRANS ? ((j%3)*3 + j/3) : j; v = W1[cc*9 + jt]; }
    else if (j == 9) v = B1[cc];
    else if (j < 19) { int k = j - 10; int jt = TRANS ? ((k%3)*3 + k/3) : k; v = W2[cc*9 + jt]; }
    __half h = __float2half(v);
    sW[i] = __halves2half2(h, h);
  }

  // ---- input staging (68x68 halo-2 window, stride 72) ----
  float m0 = 0.f, m1 = 0.f, m2 = 0.f;
  if (MODE == 0) {
    m0 = (c_==0) ? 0.299f : ((c_==1) ? -0.147f :  0.615f);
    m1 = (c_==0) ? 0.587f : ((c_==1) ? -0.289f : -0.515f);
    m2 = (c_==0) ? 0.114f : ((c_==1) ?  0.436f : -0.100f);
  }
  for (int i = tid; i < 68*68; i += 256) {
    int ly = i / 68, lx = i - ly*68;
    int gy = y0 + ly - 2, gx = x0 + lx - 2;
    float v = 0.f;
    if ((unsigned)gy < 256u && (unsigned)gx < (unsigned)IW) {
      if (MODE == 0) {
        const float* xb = xp + ((long)b_*3*512 + 2*gy)*512 + gx;
        v = m0*xb[0] + m1*xb[262144] + m2*xb[524288];
        Lw[(long)n*HW + gy*IW + gx] = v;            // side-product L (f32)
      } else if (MODE == 1) {
        v = Hw[(long)n*HW + gy*IW + gx];
      } else if (MODE == 2) {
        const float* s = (which ? Hw : Lw) + (long)n*(256*512);
        v = s[gy*512 + 2*gx];                        // even cols
      } else {
        const float* s = outp + (long)(b_*12 + (which?9:3) + c_)*65536;
        v = s[gy*256 + gx];
      }
    }
    sIn[ly*72 + lx] = __float2half(v);
  }
  __syncthreads();

  const int tx = tid & 15, ty = tid >> 4;        // 16 x 16 threads
  const int oy = y0 + ty*4, ox = x0 + tx*4;      // 4x4 outputs per thread
  const int rb = ty*4;                           // window base row in sIn

  // ---- io prefetch (hoisted: hide the HBM tail under the channel loop) ----
  float4 iov[4];
  if (MODE == 0) {
#pragma unroll
    for (int r = 0; r < 4; ++r) {
      const float* xb = xp + ((long)b_*3*512 + (2*(oy+r)+1))*512 + ox;
      float4 rr = *(const float4*)&xb[0];
      float4 gg = *(const float4*)&xb[262144];
      float4 bb = *(const float4*)&xb[524288];
      iov[r] = make_float4(m0*rr.x + m1*gg.x + m2*bb.x,
                           m0*rr.y + m1*gg.y + m2*bb.y,
                           m0*rr.z + m1*gg.z + m2*bb.z,
                           m0*rr.w + m1*gg.w + m2*bb.w);
    }
  } else if (MODE == 1) {
    const float* s = Lw + (long)n*HW;
#pragma unroll
    for (int r = 0; r < 4; ++r) iov[r] = *(const float4*)&s[(oy+r)*IW + ox];
  } else {
    const float* s = (which ? Hw : Lw) + (long)n*(256*512);
#pragma unroll
    for (int r = 0; r < 4; ++r) {
      float4 a = *(const float4*)&s[(oy+r)*512 + 2*ox];
      float4 b = *(const float4*)&s[(oy+r)*512 + 2*ox + 4];
      iov[r] = (MODE == 2) ? make_float4(a.y, a.w, b.y, b.w)    // odd cols
                           : make_float4(a.x, a.z, b.x, b.z);   // even cols
    }
  }

  // ---- hidden-map validity ----
  const bool edgex = (x0 == 0) || (x0 + 64 == IW);
  bool rowok[6];
#pragma unroll
  for (int k = 0; k < 6; ++k) rowok[k] = ((unsigned)(oy - 1 + k) < 256u);
  __half2 mE[3];
  if (edgex) {
#pragma unroll
    for (int p = 0; p < 3; ++p) {
      float a = ((unsigned)(ox - 1 + 2*p) < (unsigned)IW) ? 1.f : 0.f;
      float b = ((unsigned)(ox     + 2*p) < (unsigned)IW) ? 1.f : 0.f;
      mE[p] = __halves2half2(__float2half(a), __float2half(b));
    }
  }

  const __half2 zero2 = __builtin_bit_cast(__half2, 0u);
  const __half2 negb  = __halves2half2(__float2half(-60000.f), __float2half(-60000.f));

  float   ACCF[4][4] = {{0,0,0,0},{0,0,0,0},{0,0,0,0},{0,0,0,0}};
  __half2 ACC2[4][2] = {{zero2,zero2},{zero2,zero2},{zero2,zero2},{zero2,zero2}};

#pragma unroll 1
  for (int c0 = 0; c0 < 16; c0 += 2) {
    // ---- weights for 2 channels (10 x 16B LDS reads, broadcast) ----
    __half2 wa[20], wb[20];
    {
      const float4* qa = (const float4*)&sW[c0*20];
      const float4* qb = (const float4*)&sW[(c0+1)*20];
#pragma unroll
      for (int q = 0; q < 5; ++q) {
        float4 fa = qa[q], fb = qb[q];
        wa[4*q+0] = __builtin_bit_cast(__half2, fa.x);
        wa[4*q+1] = __builtin_bit_cast(__half2, fa.y);
        wa[4*q+2] = __builtin_bit_cast(__half2, fa.z);
        wa[4*q+3] = __builtin_bit_cast(__half2, fa.w);
        wb[4*q+0] = __builtin_bit_cast(__half2, fb.x);
        wb[4*q+1] = __builtin_bit_cast(__half2, fb.y);
        wb[4*q+2] = __builtin_bit_cast(__half2, fb.z);
        wb[4*q+3] = __builtin_bit_cast(__half2, fb.w);
      }
    }
    __half2 biasA[6], biasB[6];
#pragma unroll
    for (int k = 0; k < 6; ++k) {
      biasA[k] = rowok[k] ? wa[9] : negb;
      biasB[k] = rowok[k] ? wb[9] : negb;
    }

    // ---- rolling 3-row input window (read ONCE per 2 channels) ----
    __half2 E[3][4], O[3][3];
#pragma unroll
    for (int r = 0; r < 2; ++r) {
      const __half2* row = (const __half2*)&sIn[(rb + r)*72 + tx*4];
      E[r][0] = row[0]; E[r][1] = row[1]; E[r][2] = row[2]; E[r][3] = row[3];
      O[r][0] = oddpair(E[r][0], E[r][1]);
      O[r][1] = oddpair(E[r][1], E[r][2]);
      O[r][2] = oddpair(E[r][2], E[r][3]);
    }

#pragma unroll
    for (int kk = 0; kk < 6; ++kk) {
      const int s0 = kk % 3, s1 = (kk+1) % 3, s2 = (kk+2) % 3;
      {
        const __half2* row = (const __half2*)&sIn[(rb + kk + 2)*72 + tx*4];
        E[s2][0] = row[0]; E[s2][1] = row[1]; E[s2][2] = row[2]; E[s2][3] = row[3];
        O[s2][0] = oddpair(E[s2][0], E[s2][1]);
        O[s2][1] = oddpair(E[s2][1], E[s2][2]);
        O[s2][2] = oddpair(E[s2][2], E[s2][3]);
      }
      __half2 HA[3], HB[3];
#pragma unroll
      for (int p = 0; p < 3; ++p) {
        __half2 ha = biasA[kk], hb = biasB[kk];
        ha = __hfma2(wa[0], E[s0][p],   ha);  hb = __hfma2(wb[0], E[s0][p],   hb);
        ha = __hfma2(wa[1], O[s0][p],   ha);  hb = __hfma2(wb[1], O[s0][p],   hb);
        ha = __hfma2(wa[2], E[s0][p+1], ha);  hb = __hfma2(wb[2], E[s0][p+1], hb);
        ha = __hfma2(wa[3], E[s1][p],   ha);  hb = __hfma2(wb[3], E[s1][p],   hb);
        ha = __hfma2(wa[4], O[s1][p],   ha);  hb = __hfma2(wb[4], O[s1][p],   hb);
        ha = __hfma2(wa[5], E[s1][p+1], ha);  hb = __hfma2(wb[5], E[s1][p+1], hb);
        ha = __hfma2(wa[6], E[s2][p],   ha);  hb = __hfma2(wb[6], E[s2][p],   hb);
        ha = __hfma2(wa[7], O[s2][p],   ha);  hb = __hfma2(wb[7], O[s2][p],   hb);
        ha = __hfma2(wa[8], E[s2][p+1], ha);  hb = __hfma2(wb[8], E[s2][p+1], hb);
        HA[p] = relu2(ha);
        HB[p] = relu2(hb);
      }
      if (edgex) {
#pragma unroll
        for (int p = 0; p < 3; ++p) {
          HA[p] = __hmul2(HA[p], mE[p]);
          HB[p] = __hmul2(HB[p], mE[p]);
        }
      }
      __half2 HAo0 = oddpair(HA[0], HA[1]);
      __half2 HAo1 = oddpair(HA[1], HA[2]);
      __half2 HBo0 = oddpair(HB[0], HB[1]);
      __half2 HBo1 = oddpair(HB[1], HB[2]);
#pragma unroll
      for (int dy = 0; dy < 3; ++dy) {
        const int r = kk - dy;
        if (r >= 0 && r < 4) {
#pragma unroll
          for (int cp = 0; cp < 2; ++cp) {
            __half2 a = ACC2[r][cp];
            a = __hfma2(wa[10+dy*3+0], HA[cp],             a);
            a = __hfma2(wa[10+dy*3+1], (cp ? HAo1 : HAo0), a);
            a = __hfma2(wa[10+dy*3+2], HA[cp+1],           a);
            a = __hfma2(wb[10+dy*3+0], HB[cp],             a);
            a = __hfma2(wb[10+dy*3+1], (cp ? HBo1 : HBo0), a);
            a = __hfma2(wb[10+dy*3+2], HB[cp+1],           a);
            ACC2[r][cp] = a;
          }
        }
      }
    }
    if ((c0 & 2) != 0) {     // fold f16 group accumulator into fp32 (every 4 ch)
#pragma unroll
      for (int r = 0; r < 4; ++r)
#pragma unroll
        for (int cp = 0; cp < 2; ++cp) {
          ACCF[r][2*cp]   += __low2float(ACC2[r][cp]);
          ACCF[r][2*cp+1] += __high2float(ACC2[r][cp]);
          ACC2[r][cp] = zero2;
        }
    }
  }

  // ---- epilogue: out = io + sign*(acc + b2) ----
  const float b2 = B2[0];
  float* dst;
  if      (MODE == 0) dst = Hw + (long)n*HW;
  else if (MODE == 1) dst = Lw + (long)n*HW;
  else if (MODE == 2) dst = outp + (long)(b_*12 + (which?9:3) + c_)*65536;
  else                dst = outp + (long)(b_*12 + (which?6:0) + c_)*65536;

#pragma unroll
  for (int r = 0; r < 4; ++r) {
    float4 v;
    v.x = iov[r].x + sign * (ACCF[r][0] + b2);
    v.y = iov[r].y + sign * (ACCF[r][1] + b2);
    v.z = iov[r].z + sign * (ACCF[r][2] + b2);
    v.w = iov[r].w + sign * (ACCF[r][3] + b2);
    *(float4*)&dst[(oy + r)*IW + ox] = v;
  }
}

extern "C" void kernel_launch(void* const* d_in, const int* in_sizes, int n_in,
                              void* d_out, int out_size, void* d_ws, size_t ws_size,
                              hipStream_t stream) {
  const float* x   = (const float*)d_in[0];
  const float* Wp1 = (const float*)d_in[1];
  const float* bp1 = (const float*)d_in[2];
  const float* Wp2 = (const float*)d_in[3];
  const float* bp2 = (const float*)d_in[4];
  const float* Wu1 = (const float*)d_in[5];
  const float* bu1 = (const float*)d_in[6];
  const float* Wu2 = (const float*)d_in[7];
  const float* bu2 = (const float*)d_in[8];
  float* out = (float*)d_out;
  float* ws  = (float*)d_ws;

  // S1P: Hb' = Hb - p(L); materializes L
  k_subnet<0><<<dim3(8,4,24), 256, 0, stream>>>(x, ws, out, Wp1, bp1, Wp2, bp2);
  // S1U: L' = L + u(Hb')
  k_subnet<1><<<dim3(8,4,24), 256, 0, stream>>>(x, ws, out, Wu1, bu1, Wu2, bu2);
  // S2P: HL' = HL - pT(LL) -> q1 ; HH' = HH - pT(LH) -> q3
  k_subnet<2><<<dim3(4,4,48), 256, 0, stream>>>(x, ws, out, Wp1, bp1, Wp2, bp2);
  // S2U: LL' = LL + uT(HL') -> q0 ; LH' = LH + uT(HH') -> q2
  k_subnet<3><<<dim3(4,4,48), 256, 0, stream>>>(x, ws, out, Wu1, bu1, Wu2, bu2);
}